// Round 1
// baseline (2525.502 us; speedup 1.0000x reference)
//
#include <hip/hip_runtime.h>
#include <hip/hip_bf16.h>

#define N_NODES 10000
#define N_EDGES 160000
#define DIM     128
#define NBASIS  16
#define LDA     132   // padded LDS row stride (floats) to spread banks

__device__ __forceinline__ float silu_f(float x){
  return x * (1.0f / (1.0f + __expf(-x)));
}

// ---------------------------------------------------------------------------
// Fused 2-layer MLP: Y = silu(X @ W1 + b1) @ W2 + b2.  X is M x 128 row-major.
// 64-row tile per block, 256 threads, thread computes 8 rows x 4 cols.
// ---------------------------------------------------------------------------
template<int OUT>
__global__ __launch_bounds__(256) void mlp_fused(
    const float* __restrict__ X, int M,
    const float* __restrict__ W1, const float* __restrict__ b1,
    const float* __restrict__ W2, const float* __restrict__ b2,
    float* __restrict__ Y)
{
  __shared__ float sA[64*LDA];   // A tile, later holds H
  __shared__ float sW[32*DIM];   // streamed weight chunk

  const int tid = threadIdx.x;
  const int blk = blockIdx.x;
  const long base = (long)blk*64*DIM;

  // stage A tile (zero-fill out-of-range rows)
  #pragma unroll
  for (int i=0;i<8;i++){
    int idx4 = i*256 + tid;          // 0..2047 float4s
    int e = idx4*4;
    int row = e >> 7;
    int col = e & 127;
    float4 v = make_float4(0.f,0.f,0.f,0.f);
    if (blk*64 + row < M) v = *(const float4*)(X + base + e);
    *(float4*)(sA + row*LDA + col) = v;
  }

  const int tc = tid & 31;
  const int tr = tid >> 5;           // 0..7
  const int c0 = tc*4;
  const int r0 = tr*8;

  float acc[8][4];
  #pragma unroll
  for (int i=0;i<8;i++){ acc[i][0]=0.f;acc[i][1]=0.f;acc[i][2]=0.f;acc[i][3]=0.f; }

  // GEMM1: A @ W1
  for (int kc=0;kc<4;kc++){
    __syncthreads();
    #pragma unroll
    for (int i=0;i<4;i++){
      int idx4 = i*256+tid;          // 0..1023
      *(float4*)(sW + idx4*4) = *(const float4*)(W1 + kc*32*DIM + idx4*4);
    }
    __syncthreads();
    #pragma unroll
    for (int k=0;k<32;k+=4){
      float4 w0 = *(float4*)(sW + (k+0)*DIM + c0);
      float4 w1 = *(float4*)(sW + (k+1)*DIM + c0);
      float4 w2 = *(float4*)(sW + (k+2)*DIM + c0);
      float4 w3 = *(float4*)(sW + (k+3)*DIM + c0);
      int kk = kc*32 + k;
      #pragma unroll
      for (int i=0;i<8;i++){
        float4 a = *(float4*)(sA + (r0+i)*LDA + kk);
        acc[i][0] += a.x*w0.x + a.y*w1.x + a.z*w2.x + a.w*w3.x;
        acc[i][1] += a.x*w0.y + a.y*w1.y + a.z*w2.y + a.w*w3.y;
        acc[i][2] += a.x*w0.z + a.y*w1.z + a.z*w2.z + a.w*w3.z;
        acc[i][3] += a.x*w0.w + a.y*w1.w + a.z*w2.w + a.w*w3.w;
      }
    }
  }
  __syncthreads();

  // bias + silu -> H into sA
  {
    float4 bb = *(const float4*)(b1 + c0);
    #pragma unroll
    for (int i=0;i<8;i++){
      float4 h;
      h.x = silu_f(acc[i][0]+bb.x);
      h.y = silu_f(acc[i][1]+bb.y);
      h.z = silu_f(acc[i][2]+bb.z);
      h.w = silu_f(acc[i][3]+bb.w);
      *(float4*)(sA + (r0+i)*LDA + c0) = h;
    }
  }

  if (OUT == 1) {
    __syncthreads();
    if (tid < 32) *(float4*)(sW + tid*4) = *(const float4*)(W2 + tid*4);
    __syncthreads();
    if (tid < 64) {
      int row = blk*64 + tid;
      if (row < M) {
        float s = 0.f;
        #pragma unroll
        for (int k=0;k<DIM;k+=4){
          float4 a = *(float4*)(sA + tid*LDA + k);
          float4 w = *(float4*)(sW + k);
          s += a.x*w.x + a.y*w.y + a.z*w.z + a.w*w.w;
        }
        Y[row] = s + b2[0];
      }
    }
  } else {
    #pragma unroll
    for (int i=0;i<8;i++){ acc[i][0]=0.f;acc[i][1]=0.f;acc[i][2]=0.f;acc[i][3]=0.f; }
    for (int kc=0;kc<4;kc++){
      __syncthreads();
      #pragma unroll
      for (int i=0;i<4;i++){
        int idx4 = i*256+tid;
        *(float4*)(sW + idx4*4) = *(const float4*)(W2 + kc*32*DIM + idx4*4);
      }
      __syncthreads();
      #pragma unroll
      for (int k=0;k<32;k+=4){
        float4 w0 = *(float4*)(sW + (k+0)*DIM + c0);
        float4 w1 = *(float4*)(sW + (k+1)*DIM + c0);
        float4 w2 = *(float4*)(sW + (k+2)*DIM + c0);
        float4 w3 = *(float4*)(sW + (k+3)*DIM + c0);
        int kk = kc*32 + k;
        #pragma unroll
        for (int i=0;i<8;i++){
          float4 a = *(float4*)(sA + (r0+i)*LDA + kk);
          acc[i][0] += a.x*w0.x + a.y*w1.x + a.z*w2.x + a.w*w3.x;
          acc[i][1] += a.x*w0.y + a.y*w1.y + a.z*w2.y + a.w*w3.y;
          acc[i][2] += a.x*w0.z + a.y*w1.z + a.z*w2.z + a.w*w3.z;
          acc[i][3] += a.x*w0.w + a.y*w1.w + a.z*w2.w + a.w*w3.w;
        }
      }
    }
    float4 bb = *(const float4*)(b2 + c0);
    #pragma unroll
    for (int i=0;i<8;i++){
      int row = blk*64 + r0 + i;
      if (row < M){
        float4 o;
        o.x = acc[i][0]+bb.x; o.y = acc[i][1]+bb.y;
        o.z = acc[i][2]+bb.z; o.w = acc[i][3]+bb.w;
        *(float4*)(Y + (long)row*DIM + c0) = o;
      }
    }
  }
}

// ---------------------------------------------------------------------------
// row_start[n] = lower_bound(edge_src, n)  (edge_src is sorted)
// ---------------------------------------------------------------------------
__global__ void seg_offsets(const int* __restrict__ esrc, int* __restrict__ row_start){
  int t = blockIdx.x*256 + threadIdx.x;
  if (t > N_NODES) return;
  int lo = 0, hi = N_EDGES;
  while (lo < hi){ int mid = (lo+hi)>>1; if (esrc[mid] < t) lo = mid+1; else hi = mid; }
  row_start[t] = lo;
}

// xi init + fi zero
__global__ void init_nodes(const int* __restrict__ species,
                           const float* __restrict__ spW, const float* __restrict__ spB,
                           float* __restrict__ xi, float* __restrict__ fi){
  int idx = blockIdx.x*256 + threadIdx.x;   // < N*128
  int n = idx >> 7, d = idx & 127;
  xi[idx] = spW[species[n]*DIM + d] + spB[d];
  fi[n*384 + d*3 + 0] = 0.f;
  fi[n*384 + d*3 + 1] = 0.f;
  fi[n*384 + d*3 + 2] = 0.f;
}

// dir = vec/dist*sw ; rb = exp(-eta*(d-c_j)^2)
__global__ void edge_geom(const float* __restrict__ dist, const float* __restrict__ vec,
                          const float* __restrict__ swv,
                          float* __restrict__ dir, float* __restrict__ rb){
  int e = blockIdx.x*256 + threadIdx.x;
  if (e >= N_EDGES) return;
  float d = dist[e];
  float s = swv[e];
  float inv = s / d;
  dir[e*3+0] = vec[e*3+0]*inv;
  dir[e*3+1] = vec[e*3+1]*inv;
  dir[e*3+2] = vec[e*3+2]*inv;
  const float eta = (16.0f/5.0f)*(16.0f/5.0f);
  #pragma unroll
  for (int j=0;j<NBASIS;j++){
    float c = (float)j * (5.0f/15.0f);
    float t = d - c;
    rb[e*NBASIS + j] = __expf(-eta*t*t);
  }
}

// mij = ai[src]*ai[dst]*(rb@radW + radB)*sw ; 16 edges per block
__global__ __launch_bounds__(256) void mij_kernel(
    const float* __restrict__ ai, const int* __restrict__ esrc, const int* __restrict__ edst,
    const float* __restrict__ swv, const float* __restrict__ rb,
    const float* __restrict__ radW, const float* __restrict__ radB,
    float* __restrict__ mij)
{
  __shared__ float sRW[NBASIS*DIM];
  __shared__ float sRB[DIM];
  __shared__ float sRb[16*NBASIS];
  __shared__ int   sS[16], sD[16];
  __shared__ float sSw[16];
  int tid = threadIdx.x;
  int e0 = blockIdx.x * 16;
  #pragma unroll
  for (int i=0;i<2;i++){
    int idx4 = i*256 + tid;
    *(float4*)(sRW + idx4*4) = *(const float4*)(radW + idx4*4);
  }
  sRb[tid] = rb[e0*NBASIS + tid];
  if (tid < DIM) sRB[tid] = radB[tid];
  if (tid < 16){
    sS[tid]  = esrc[e0+tid];
    sD[tid]  = edst[e0+tid];
    sSw[tid] = swv[e0+tid];
  }
  __syncthreads();
  #pragma unroll
  for (int i=0;i<8;i++){
    int o = i*256 + tid;
    int el = o >> 7, d = o & 127;
    float acc = 0.f;
    #pragma unroll
    for (int j=0;j<NBASIS;j++) acc += sRb[el*NBASIS+j]*sRW[j*DIM+d];
    float Dij = acc + sRB[d];
    float m = ai[sS[el]*DIM + d] * ai[sD[el]*DIM + d] * Dij * sSw[el];
    mij[(long)(e0+el)*DIM + d] = m;
  }
}

// xi += segment_sum(mij)
__global__ __launch_bounds__(128) void segsum_xi(const float* __restrict__ mij,
                                                 const int* __restrict__ row_start,
                                                 float* __restrict__ xi){
  int n = blockIdx.x, d = threadIdx.x;
  int s0 = row_start[n], s1 = row_start[n+1];
  float s = 0.f;
  for (int e=s0;e<s1;e++) s += mij[(long)e*DIM + d];
  xi[n*DIM+d] += s;
}

// fi += segment_sum( f(mij)[:,d] * F(mij) * dir[:,k] )
__global__ __launch_bounds__(128) void fi_acc(const float* __restrict__ ef, const float* __restrict__ eF,
                                              const float* __restrict__ dir,
                                              const int* __restrict__ row_start,
                                              float* __restrict__ fi){
  int n = blockIdx.x, d = threadIdx.x;
  int s0 = row_start[n], s1 = row_start[n+1];
  float a0=0.f,a1=0.f,a2=0.f;
  for (int e=s0;e<s1;e++){
    float s = ef[(long)e*DIM+d]*eF[e];
    a0 += s*dir[e*3+0];
    a1 += s*dir[e*3+1];
    a2 += s*dir[e*3+2];
  }
  fi[n*384+d*3+0] += a0;
  fi[n*384+d*3+1] += a1;
  fi[n*384+d*3+2] += a2;
}

// di update + scal = sum(fi*di, -1)
__global__ __launch_bounds__(128) void discal(const float* __restrict__ Rv, const float* __restrict__ ephi,
                                              const float* __restrict__ swv,
                                              const int* __restrict__ row_start,
                                              const float* __restrict__ fi,
                                              float* __restrict__ di, float* __restrict__ scal, int layer){
  int n = blockIdx.x, d = threadIdx.x;
  float Rv_ = Rv[n*DIM+d];
  float phi = 0.f;
  if (layer > 0){
    int s0 = row_start[n], s1 = row_start[n+1];
    for (int e=s0;e<s1;e++) phi += ephi[(long)e*DIM+d]*swv[e];
  }
  float sc = 0.f;
  #pragma unroll
  for (int k=0;k<3;k++){
    float fiv = fi[n*384+d*3+k];
    float delta = Rv_*fiv;
    float dv = (layer==0) ? delta : phi*di[n*384+d*3+k] + delta;
    di[n*384+d*3+k] = dv;
    sc += fiv*dv;
  }
  scal[n*DIM+d] = sc;
}

// xi -= u * scal
__global__ void xi_update(float* __restrict__ xi, const float* __restrict__ uv,
                          const float* __restrict__ scal){
  int idx = blockIdx.x*256 + threadIdx.x;
  xi[idx] -= uv[idx]*scal[idx];
}

extern "C" void kernel_launch(void* const* d_in, const int* in_sizes, int n_in,
                              void* d_out, int out_size, void* d_ws, size_t ws_size,
                              hipStream_t stream) {
  const int*   species = (const int*)  d_in[0];
  const int*   esrc    = (const int*)  d_in[1];
  const int*   edst    = (const int*)  d_in[2];
  const float* dist    = (const float*)d_in[3];
  const float* vec     = (const float*)d_in[4];
  const float* swv     = (const float*)d_in[5];
  const float* spW     = (const float*)d_in[6];
  const float* spB     = (const float*)d_in[7];
  const float* radW    = (const float*)d_in[8];
  const float* radB    = (const float*)d_in[9];
  const float* aW1=(const float*)d_in[10], *aB1=(const float*)d_in[11], *aW2=(const float*)d_in[12], *aB2=(const float*)d_in[13];
  const float* FW1=(const float*)d_in[14], *FB1=(const float*)d_in[15], *FW2=(const float*)d_in[16], *FB2=(const float*)d_in[17];
  const float* fW1=(const float*)d_in[18], *fB1=(const float*)d_in[19], *fW2=(const float*)d_in[20], *fB2=(const float*)d_in[21];
  const float* RW1=(const float*)d_in[22], *RB1=(const float*)d_in[23], *RW2=(const float*)d_in[24], *RB2=(const float*)d_in[25];
  const float* rW1=(const float*)d_in[26], *rB1=(const float*)d_in[27], *rW2=(const float*)d_in[28], *rB2=(const float*)d_in[29];
  const float* uW1=(const float*)d_in[30], *uB1=(const float*)d_in[31], *uW2=(const float*)d_in[32], *uB2=(const float*)d_in[33];

  const long NF = (long)N_NODES*DIM;   // 1,280,000
  float* ws   = (float*)d_ws;
  float* xi   = ws;
  float* ai   = xi   + NF;
  float* Rv   = ai   + NF;
  float* uv   = Rv   + NF;
  float* scal = uv   + NF;
  float* fi   = scal + NF;
  float* di   = fi   + 3*NF;
  float* mij  = di   + 3*NF;
  float* ef   = mij  + (long)N_EDGES*DIM;
  float* eF   = ef   + (long)N_EDGES*DIM;
  float* dir  = eF   + N_EDGES;
  float* rb   = dir  + 3L*N_EDGES;
  int* row_start = (int*)(rb + 16L*N_EDGES);

  seg_offsets<<<40, 256, 0, stream>>>(esrc, row_start);
  init_nodes<<<(int)(NF/256), 256, 0, stream>>>(species, spW, spB, xi, fi);
  edge_geom<<<N_EDGES/256, 256, 0, stream>>>(dist, vec, swv, dir, rb);

  const int nodeBlocks = (N_NODES + 63)/64;   // 157
  const int edgeBlocks = N_EDGES/64;          // 2500

  for (int l=0;l<3;l++){
    const long wo = (long)l*DIM*DIM;
    const long bo = (long)l*DIM;

    // ai = mlp_a(xi)
    mlp_fused<DIM><<<nodeBlocks, 256, 0, stream>>>(xi, N_NODES, aW1+wo, aB1+bo, aW2+wo, aB2+bo, ai);
    // mij
    mij_kernel<<<N_EDGES/16, 256, 0, stream>>>(ai, esrc, edst, swv, rb,
                                               radW + (long)l*NBASIS*DIM, radB + bo, mij);
    // xi += segsum(mij)
    segsum_xi<<<N_NODES, 128, 0, stream>>>(mij, row_start, xi);
    // eF = mlp_F(mij)  (scalar out)
    mlp_fused<1><<<edgeBlocks, 256, 0, stream>>>(mij, N_EDGES, FW1+wo, FB1+bo, FW2+(long)l*DIM, FB2+l, eF);
    // ef = mlp_f(mij)
    mlp_fused<DIM><<<edgeBlocks, 256, 0, stream>>>(mij, N_EDGES, fW1+wo, fB1+bo, fW2+wo, fB2+bo, ef);
    // fi += segsum(ef * eF * dir)
    fi_acc<<<N_NODES, 128, 0, stream>>>(ef, eF, dir, row_start, fi);
    // ephi = mlp_r(mij)  (reuse ef buffer)
    if (l > 0)
      mlp_fused<DIM><<<edgeBlocks, 256, 0, stream>>>(mij, N_EDGES, rW1+wo, rB1+bo, rW2+wo, rB2+bo, ef);
    // Rv = mlp_R(xi)
    mlp_fused<DIM><<<nodeBlocks, 256, 0, stream>>>(xi, N_NODES, RW1+wo, RB1+bo, RW2+wo, RB2+bo, Rv);
    // di, scal
    discal<<<N_NODES, 128, 0, stream>>>(Rv, ef, swv, row_start, fi, di, scal, l);
    // uv = mlp_u(xi)
    mlp_fused<DIM><<<nodeBlocks, 256, 0, stream>>>(xi, N_NODES, uW1+wo, uB1+bo, uW2+wo, uB2+bo, uv);
    // xi -= uv*scal
    xi_update<<<(int)(NF/256), 256, 0, stream>>>(xi, uv, scal);
  }

  hipMemcpyAsync(d_out, xi, (size_t)NF*sizeof(float), hipMemcpyDeviceToDevice, stream);
}

// Round 2
// 1038.618 us; speedup vs baseline: 2.4316x; 2.4316x over previous
//
#include <hip/hip_runtime.h>
#include <hip/hip_bf16.h>

#define N_NODES 10000
#define N_EDGES 160000
#define DIM     128
#define NBASIS  16
#define LDT     136   // LDS row stride in bf16 elems (+8 pad: 2-way bank alias = free)

typedef __bf16 bf16x8 __attribute__((ext_vector_type(8)));
typedef __bf16 bf16x4 __attribute__((ext_vector_type(4)));
typedef float  f32x4  __attribute__((ext_vector_type(4)));

__device__ __forceinline__ float silu_f(float x){
  return x * (1.0f / (1.0f + __expf(-x)));
}

// ---------------------------------------------------------------------------
// Fused MFMA 2-layer MLP: Y = silu(X @ W1 + b1) @ W2 + b2
// X: M x 128 fp32 (converted to bf16 while staging). W1t/W2t: bf16, transposed
// [n][k] so B-frag LDS reads are k-contiguous. 128-row tile, 256 thr = 4 waves,
// wave w owns rows [32w,32w+32): 2 row-tiles x 8 col-tiles of 16x16x32 MFMA.
// ---------------------------------------------------------------------------
template<int OUT>
__global__ __launch_bounds__(256,2) void mlp_mfma(
    const float* __restrict__ X, int M,
    const __bf16* __restrict__ W1t, const float* __restrict__ b1,
    const __bf16* __restrict__ W2t, const float* __restrict__ W2v,
    const float* __restrict__ b2, float* __restrict__ Y)
{
  __shared__ __bf16 sX[128*LDT];
  __shared__ __bf16 sW[128*LDT];
  const int tid  = threadIdx.x;
  const int row0 = blockIdx.x*128;

  // stage X tile (fp32 -> bf16), zero-fill rows >= M
  #pragma unroll
  for (int it=0; it<16; ++it){
    int idx4 = it*256 + tid;
    int e = idx4*4, row = e>>7, col = e&127;
    float4 v = make_float4(0.f,0.f,0.f,0.f);
    if (row0+row < M) v = *(const float4*)(X + (long)(row0+row)*DIM + col);
    bf16x4 h; h[0]=(__bf16)v.x; h[1]=(__bf16)v.y; h[2]=(__bf16)v.z; h[3]=(__bf16)v.w;
    *(bf16x4*)&sX[row*LDT+col] = h;
  }
  // stage W1t (already bf16, [n][k])
  #pragma unroll
  for (int it=0; it<8; ++it){
    int idx8 = it*256 + tid;
    int e = idx8*8, n = e>>7, k = e&127;
    *(bf16x8*)&sW[n*LDT+k] = *(const bf16x8*)(W1t + e);
  }
  __syncthreads();

  const int lane = tid & 63;
  const int wv   = tid >> 6;
  const int l15  = lane & 15;
  const int quad = lane >> 4;

  f32x4 acc[2][8];
  #pragma unroll
  for (int mi=0; mi<2; ++mi)
    #pragma unroll
    for (int ni=0; ni<8; ++ni) acc[mi][ni] = (f32x4){0.f,0.f,0.f,0.f};

  // GEMM1: H = X @ W1
  #pragma unroll
  for (int kc=0; kc<4; ++kc){
    int kb = kc*32 + quad*8;
    bf16x8 aA[2];
    aA[0] = *(bf16x8*)&sX[(wv*32      + l15)*LDT + kb];
    aA[1] = *(bf16x8*)&sX[(wv*32 + 16 + l15)*LDT + kb];
    #pragma unroll
    for (int ni=0; ni<8; ++ni){
      bf16x8 bB = *(bf16x8*)&sW[(ni*16 + l15)*LDT + kb];
      acc[0][ni] = __builtin_amdgcn_mfma_f32_16x16x32_bf16(aA[0], bB, acc[0][ni],0,0,0);
      acc[1][ni] = __builtin_amdgcn_mfma_f32_16x16x32_bf16(aA[1], bB, acc[1][ni],0,0,0);
    }
  }
  // epilogue 1: bias+silu -> H back into sX (wave-private rows, no sync needed)
  #pragma unroll
  for (int mi=0; mi<2; ++mi){
    #pragma unroll
    for (int ni=0; ni<8; ++ni){
      int col = ni*16 + l15;
      float bb = b1[col];
      #pragma unroll
      for (int r=0; r<4; ++r){
        int row = wv*32 + mi*16 + quad*4 + r;
        sX[row*LDT+col] = (__bf16)silu_f(acc[mi][ni][r] + bb);
      }
    }
  }

  if (OUT == 1){
    __syncthreads();   // F-epilogue reads rows across waves
    if (tid < 128){
      float s = 0.f;
      #pragma unroll
      for (int k=0;k<128;k++) s += (float)sX[tid*LDT+k] * W2v[k];
      int rg = row0 + tid;
      if (rg < M) Y[rg] = s + b2[0];
    }
    return;
  }

  __syncthreads();                      // all GEMM1 sW reads done
  #pragma unroll
  for (int it=0; it<8; ++it){
    int idx8 = it*256 + tid;
    int e = idx8*8, n = e>>7, k = e&127;
    *(bf16x8*)&sW[n*LDT+k] = *(const bf16x8*)(W2t + e);
  }
  __syncthreads();

  #pragma unroll
  for (int mi=0; mi<2; ++mi)
    #pragma unroll
    for (int ni=0; ni<8; ++ni) acc[mi][ni] = (f32x4){0.f,0.f,0.f,0.f};

  // GEMM2: Y = H @ W2
  #pragma unroll
  for (int kc=0; kc<4; ++kc){
    int kb = kc*32 + quad*8;
    bf16x8 aA[2];
    aA[0] = *(bf16x8*)&sX[(wv*32      + l15)*LDT + kb];
    aA[1] = *(bf16x8*)&sX[(wv*32 + 16 + l15)*LDT + kb];
    #pragma unroll
    for (int ni=0; ni<8; ++ni){
      bf16x8 bB = *(bf16x8*)&sW[(ni*16 + l15)*LDT + kb];
      acc[0][ni] = __builtin_amdgcn_mfma_f32_16x16x32_bf16(aA[0], bB, acc[0][ni],0,0,0);
      acc[1][ni] = __builtin_amdgcn_mfma_f32_16x16x32_bf16(aA[1], bB, acc[1][ni],0,0,0);
    }
  }
  #pragma unroll
  for (int mi=0; mi<2; ++mi){
    #pragma unroll
    for (int ni=0; ni<8; ++ni){
      int col = ni*16 + l15;
      float bb = b2[col];
      #pragma unroll
      for (int r=0; r<4; ++r){
        int row = row0 + wv*32 + mi*16 + quad*4 + r;
        if (row < M) Y[(long)row*DIM + col] = acc[mi][ni][r] + bb;
      }
    }
  }
}

// ---------------------------------------------------------------------------
// Convert + transpose fp32 W[k][n] -> bf16 Wt[n][k]. One block per matrix.
// ---------------------------------------------------------------------------
struct WPtrs { const float* p[11]; };

__global__ __launch_bounds__(256) void convert_wt(WPtrs wp, __bf16* __restrict__ dst){
  __shared__ __bf16 s[128*129];
  int mat = blockIdx.x;          // t*3 + l
  int t = mat/3, l = mat%3;
  const float* src = wp.p[t] + (size_t)l*16384;
  __bf16* out = dst + (size_t)mat*16384;
  for (int it=0; it<64; ++it){
    int idx = it*256 + threadIdx.x;
    int k = idx>>7, n = idx&127;
    s[k*129+n] = (__bf16)src[idx];
  }
  __syncthreads();
  for (int it=0; it<64; ++it){
    int idx = it*256 + threadIdx.x;
    int n = idx>>7, k = idx&127;
    out[idx] = s[k*129+n];
  }
}

// ---------------------------------------------------------------------------
// row_start[n] = lower_bound(edge_src, n)  (edge_src is sorted)
// ---------------------------------------------------------------------------
__global__ void seg_offsets(const int* __restrict__ esrc, int* __restrict__ row_start){
  int t = blockIdx.x*256 + threadIdx.x;
  if (t > N_NODES) return;
  int lo = 0, hi = N_EDGES;
  while (lo < hi){ int mid = (lo+hi)>>1; if (esrc[mid] < t) lo = mid+1; else hi = mid; }
  row_start[t] = lo;
}

// xi init + fi zero
__global__ void init_nodes(const int* __restrict__ species,
                           const float* __restrict__ spW, const float* __restrict__ spB,
                           float* __restrict__ xi, float* __restrict__ fi){
  int idx = blockIdx.x*256 + threadIdx.x;   // < N*128
  int n = idx >> 7, d = idx & 127;
  xi[idx] = spW[species[n]*DIM + d] + spB[d];
  fi[n*384 + d*3 + 0] = 0.f;
  fi[n*384 + d*3 + 1] = 0.f;
  fi[n*384 + d*3 + 2] = 0.f;
}

// dir = vec/dist*sw ; rb = exp(-eta*(d-c_j)^2)
__global__ void edge_geom(const float* __restrict__ dist, const float* __restrict__ vec,
                          const float* __restrict__ swv,
                          float* __restrict__ dir, float* __restrict__ rb){
  int e = blockIdx.x*256 + threadIdx.x;
  if (e >= N_EDGES) return;
  float d = dist[e];
  float s = swv[e];
  float inv = s / d;
  dir[e*3+0] = vec[e*3+0]*inv;
  dir[e*3+1] = vec[e*3+1]*inv;
  dir[e*3+2] = vec[e*3+2]*inv;
  const float eta = (16.0f/5.0f)*(16.0f/5.0f);
  #pragma unroll
  for (int j=0;j<NBASIS;j++){
    float c = (float)j * (5.0f/15.0f);
    float t = d - c;
    rb[e*NBASIS + j] = __expf(-eta*t*t);
  }
}

// mij = ai[src]*ai[dst]*(rb@radW + radB)*sw ; 16 edges per block
__global__ __launch_bounds__(256) void mij_kernel(
    const float* __restrict__ ai, const int* __restrict__ esrc, const int* __restrict__ edst,
    const float* __restrict__ swv, const float* __restrict__ rb,
    const float* __restrict__ radW, const float* __restrict__ radB,
    float* __restrict__ mij)
{
  __shared__ float sRW[NBASIS*DIM];
  __shared__ float sRB[DIM];
  __shared__ float sRb[16*NBASIS];
  __shared__ int   sS[16], sD[16];
  __shared__ float sSw[16];
  int tid = threadIdx.x;
  int e0 = blockIdx.x * 16;
  #pragma unroll
  for (int i=0;i<2;i++){
    int idx4 = i*256 + tid;
    *(float4*)(sRW + idx4*4) = *(const float4*)(radW + idx4*4);
  }
  sRb[tid] = rb[e0*NBASIS + tid];
  if (tid < DIM) sRB[tid] = radB[tid];
  if (tid < 16){
    sS[tid]  = esrc[e0+tid];
    sD[tid]  = edst[e0+tid];
    sSw[tid] = swv[e0+tid];
  }
  __syncthreads();
  #pragma unroll
  for (int i=0;i<8;i++){
    int o = i*256 + tid;
    int el = o >> 7, d = o & 127;
    float acc = 0.f;
    #pragma unroll
    for (int j=0;j<NBASIS;j++) acc += sRb[el*NBASIS+j]*sRW[j*DIM+d];
    float Dij = acc + sRB[d];
    float m = ai[sS[el]*DIM + d] * ai[sD[el]*DIM + d] * Dij * sSw[el];
    mij[(long)(e0+el)*DIM + d] = m;
  }
}

// xi += segment_sum(mij)
__global__ __launch_bounds__(128) void segsum_xi(const float* __restrict__ mij,
                                                 const int* __restrict__ row_start,
                                                 float* __restrict__ xi){
  int n = blockIdx.x, d = threadIdx.x;
  int s0 = row_start[n], s1 = row_start[n+1];
  float s = 0.f;
  for (int e=s0;e<s1;e++) s += mij[(long)e*DIM + d];
  xi[n*DIM+d] += s;
}

// fi += segment_sum( f(mij)[:,d] * F(mij) * dir[:,k] )
__global__ __launch_bounds__(128) void fi_acc(const float* __restrict__ ef, const float* __restrict__ eF,
                                              const float* __restrict__ dir,
                                              const int* __restrict__ row_start,
                                              float* __restrict__ fi){
  int n = blockIdx.x, d = threadIdx.x;
  int s0 = row_start[n], s1 = row_start[n+1];
  float a0=0.f,a1=0.f,a2=0.f;
  for (int e=s0;e<s1;e++){
    float s = ef[(long)e*DIM+d]*eF[e];
    a0 += s*dir[e*3+0];
    a1 += s*dir[e*3+1];
    a2 += s*dir[e*3+2];
  }
  fi[n*384+d*3+0] += a0;
  fi[n*384+d*3+1] += a1;
  fi[n*384+d*3+2] += a2;
}

// di update + scal = sum(fi*di, -1)
__global__ __launch_bounds__(128) void discal(const float* __restrict__ Rv, const float* __restrict__ ephi,
                                              const float* __restrict__ swv,
                                              const int* __restrict__ row_start,
                                              const float* __restrict__ fi,
                                              float* __restrict__ di, float* __restrict__ scal, int layer){
  int n = blockIdx.x, d = threadIdx.x;
  float Rv_ = Rv[n*DIM+d];
  float phi = 0.f;
  if (layer > 0){
    int s0 = row_start[n], s1 = row_start[n+1];
    for (int e=s0;e<s1;e++) phi += ephi[(long)e*DIM+d]*swv[e];
  }
  float sc = 0.f;
  #pragma unroll
  for (int k=0;k<3;k++){
    float fiv = fi[n*384+d*3+k];
    float delta = Rv_*fiv;
    float dv = (layer==0) ? delta : phi*di[n*384+d*3+k] + delta;
    di[n*384+d*3+k] = dv;
    sc += fiv*dv;
  }
  scal[n*DIM+d] = sc;
}

// xi -= u * scal
__global__ void xi_update(float* __restrict__ xi, const float* __restrict__ uv,
                          const float* __restrict__ scal){
  int idx = blockIdx.x*256 + threadIdx.x;
  xi[idx] -= uv[idx]*scal[idx];
}

extern "C" void kernel_launch(void* const* d_in, const int* in_sizes, int n_in,
                              void* d_out, int out_size, void* d_ws, size_t ws_size,
                              hipStream_t stream) {
  const int*   species = (const int*)  d_in[0];
  const int*   esrc    = (const int*)  d_in[1];
  const int*   edst    = (const int*)  d_in[2];
  const float* dist    = (const float*)d_in[3];
  const float* vec     = (const float*)d_in[4];
  const float* swv     = (const float*)d_in[5];
  const float* spW     = (const float*)d_in[6];
  const float* spB     = (const float*)d_in[7];
  const float* radW    = (const float*)d_in[8];
  const float* radB    = (const float*)d_in[9];
  const float* aW1=(const float*)d_in[10], *aB1=(const float*)d_in[11], *aW2=(const float*)d_in[12], *aB2=(const float*)d_in[13];
  const float* FW1=(const float*)d_in[14], *FB1=(const float*)d_in[15], *FW2=(const float*)d_in[16], *FB2=(const float*)d_in[17];
  const float* fW1=(const float*)d_in[18], *fB1=(const float*)d_in[19], *fW2=(const float*)d_in[20], *fB2=(const float*)d_in[21];
  const float* RW1=(const float*)d_in[22], *RB1=(const float*)d_in[23], *RW2=(const float*)d_in[24], *RB2=(const float*)d_in[25];
  const float* rW1=(const float*)d_in[26], *rB1=(const float*)d_in[27], *rW2=(const float*)d_in[28], *rB2=(const float*)d_in[29];
  const float* uW1=(const float*)d_in[30], *uB1=(const float*)d_in[31], *uW2=(const float*)d_in[32], *uB2=(const float*)d_in[33];

  const long NF = (long)N_NODES*DIM;   // 1,280,000
  float* ws   = (float*)d_ws;
  float* xi   = ws;
  float* ai   = xi   + NF;
  float* Rv   = ai   + NF;
  float* uv   = Rv   + NF;
  float* scal = uv   + NF;
  float* fi   = scal + NF;
  float* di   = fi   + 3*NF;
  float* mij  = di   + 3*NF;
  float* ef   = mij  + (long)N_EDGES*DIM;
  float* eF   = ef   + (long)N_EDGES*DIM;
  float* dir  = eF   + N_EDGES;
  float* rb   = dir  + 3L*N_EDGES;
  int* row_start = (int*)(rb + 16L*N_EDGES);
  size_t wt_off = (size_t)((char*)(row_start + N_NODES + 2) - (char*)d_ws);
  wt_off = (wt_off + 15) & ~(size_t)15;
  __bf16* wt = (__bf16*)((char*)d_ws + wt_off);   // 33 x 128x128 bf16

  // bf16 transposed weights: tensor order a1,a2,F1,f1,f2,R1,R2,r1,r2,u1,u2
  WPtrs wp;
  wp.p[0]=aW1; wp.p[1]=aW2; wp.p[2]=FW1; wp.p[3]=fW1; wp.p[4]=fW2;
  wp.p[5]=RW1; wp.p[6]=RW2; wp.p[7]=rW1; wp.p[8]=rW2; wp.p[9]=uW1; wp.p[10]=uW2;
  convert_wt<<<33, 256, 0, stream>>>(wp, wt);

  seg_offsets<<<40, 256, 0, stream>>>(esrc, row_start);
  init_nodes<<<(int)(NF/256), 256, 0, stream>>>(species, spW, spB, xi, fi);
  edge_geom<<<N_EDGES/256, 256, 0, stream>>>(dist, vec, swv, dir, rb);

  const int nodeBlocks = (N_NODES + 127)/128;   // 79
  const int edgeBlocks = N_EDGES/128;           // 1250
  #define WT(t,l) (wt + (size_t)((t)*3+(l))*16384)

  for (int l=0;l<3;l++){
    const long bo = (long)l*DIM;

    // ai = mlp_a(xi)
    mlp_mfma<DIM><<<nodeBlocks, 256, 0, stream>>>(xi, N_NODES, WT(0,l), aB1+bo, WT(1,l), nullptr, aB2+bo, ai);
    // mij
    mij_kernel<<<N_EDGES/16, 256, 0, stream>>>(ai, esrc, edst, swv, rb,
                                               radW + (long)l*NBASIS*DIM, radB + bo, mij);
    // xi += segsum(mij)
    segsum_xi<<<N_NODES, 128, 0, stream>>>(mij, row_start, xi);
    // eF = mlp_F(mij)  (scalar out)
    mlp_mfma<1><<<edgeBlocks, 256, 0, stream>>>(mij, N_EDGES, WT(2,l), FB1+bo, nullptr, FW2+(long)l*DIM, FB2+l, eF);
    // ef = mlp_f(mij)
    mlp_mfma<DIM><<<edgeBlocks, 256, 0, stream>>>(mij, N_EDGES, WT(3,l), fB1+bo, WT(4,l), nullptr, fB2+bo, ef);
    // fi += segsum(ef * eF * dir)
    fi_acc<<<N_NODES, 128, 0, stream>>>(ef, eF, dir, row_start, fi);
    // ephi = mlp_r(mij)  (reuse ef buffer)
    if (l > 0)
      mlp_mfma<DIM><<<edgeBlocks, 256, 0, stream>>>(mij, N_EDGES, WT(7,l), rB1+bo, WT(8,l), nullptr, rB2+bo, ef);
    // Rv = mlp_R(xi)
    mlp_mfma<DIM><<<nodeBlocks, 256, 0, stream>>>(xi, N_NODES, WT(5,l), RB1+bo, WT(6,l), nullptr, RB2+bo, Rv);
    // di, scal
    discal<<<N_NODES, 128, 0, stream>>>(Rv, ef, swv, row_start, fi, di, scal, l);
    // uv = mlp_u(xi)
    mlp_mfma<DIM><<<nodeBlocks, 256, 0, stream>>>(xi, N_NODES, WT(9,l), uB1+bo, WT(10,l), nullptr, uB2+bo, uv);
    // xi -= uv*scal
    xi_update<<<(int)(NF/256), 256, 0, stream>>>(xi, uv, scal);
  }

  hipMemcpyAsync(d_out, xi, (size_t)NF*sizeof(float), hipMemcpyDeviceToDevice, stream);
}